// Round 1
// baseline (1577.050 us; speedup 1.0000x reference)
//
#include <hip/hip_runtime.h>
#include <cstddef>
#include <cstdint>

#define N_PTS 16384
#define K_PTS 1024
#define D_DIM 512
#define EPS_F 0.1f
#define ITERS 20
#define MU_F (1.0f/16384.0f)
#define NU_F (1.0f/1024.0f)

__device__ __forceinline__ float wave_reduce_sum(float s) {
#pragma unroll
  for (int off = 32; off > 0; off >>= 1) s += __shfl_xor(s, off, 64);
  return s;
}
__device__ __forceinline__ float wave_reduce_max(float s) {
#pragma unroll
  for (int off = 32; off > 0; off >>= 1) s = fmaxf(s, __shfl_xor(s, off, 64));
  return s;
}

// ---------------------------------------------------------------- init
__global__ __launch_bounds__(256) void init_kernel(float* __restrict__ accum,
                                                   unsigned int* __restrict__ maxbits,
                                                   float* __restrict__ loss) {
  int i = blockIdx.x * 256 + threadIdx.x;
  const int total = (ITERS + 1) * K_PTS;
  if (i < total) accum[i] = 0.0f;
  if (blockIdx.x == 0 && threadIdx.x == 0) { *maxbits = 0u; *loss = 0.0f; }
}

// ---------------------------------------------------------------- row norms
__global__ __launch_bounds__(256) void rownorm_kernel(const float* __restrict__ A,
                                                      float* __restrict__ out, int rows) {
  int wave = (blockIdx.x * 256 + threadIdx.x) >> 6;
  int lane = threadIdx.x & 63;
  if (wave >= rows) return;
  const float4* rp = (const float4*)(A + (size_t)wave * D_DIM);
  float4 a = rp[lane];
  float4 b = rp[lane + 64];
  float s = a.x*a.x + a.y*a.y + a.z*a.z + a.w*a.w
          + b.x*b.x + b.y*b.y + b.z*b.z + b.w*b.w;
  s = wave_reduce_sum(s);
  if (lane == 0) out[wave] = s;
}

// ---------------------------------------------------------------- fp32 GEMM: C = dx + pn - 2*x@p^T, track max
__global__ __launch_bounds__(256) void gemm_kernel(const float* __restrict__ X,
                                                   const float* __restrict__ P,
                                                   const float* __restrict__ dx,
                                                   const float* __restrict__ pn,
                                                   float* __restrict__ C,
                                                   unsigned int* __restrict__ maxbits) {
  __shared__ float As[16][68];
  __shared__ float Bs[16][68];
  const int tid = threadIdx.x;
  const int tx = tid & 15, ty = tid >> 4;
  const int m0 = blockIdx.y * 64, k0 = blockIdx.x * 64;
  const int lr = tid >> 2;          // 0..63 (tile row to load)
  const int ld = (tid & 3) * 4;     // 0,4,8,12 (d-offset)
  float acc[4][4] = {};
  for (int d0 = 0; d0 < D_DIM; d0 += 16) {
    float4 a4 = *(const float4*)(X + (size_t)(m0 + lr) * D_DIM + d0 + ld);
    float4 b4 = *(const float4*)(P + (size_t)(k0 + lr) * D_DIM + d0 + ld);
    As[ld + 0][lr] = a4.x; As[ld + 1][lr] = a4.y; As[ld + 2][lr] = a4.z; As[ld + 3][lr] = a4.w;
    Bs[ld + 0][lr] = b4.x; Bs[ld + 1][lr] = b4.y; Bs[ld + 2][lr] = b4.z; Bs[ld + 3][lr] = b4.w;
    __syncthreads();
#pragma unroll
    for (int d = 0; d < 16; d++) {
      float a[4], b[4];
#pragma unroll
      for (int i = 0; i < 4; i++) a[i] = As[d][ty * 4 + i];
#pragma unroll
      for (int j = 0; j < 4; j++) b[j] = Bs[d][tx * 4 + j];
#pragma unroll
      for (int i = 0; i < 4; i++)
#pragma unroll
        for (int j = 0; j < 4; j++)
          acc[i][j] += a[i] * b[j];
    }
    __syncthreads();
  }
  float lmax = -3.4e38f;
#pragma unroll
  for (int i = 0; i < 4; i++) {
    int row = m0 + ty * 4 + i;
    float dxi = dx[row];
    float tmp[4];
#pragma unroll
    for (int j = 0; j < 4; j++) {
      int col = k0 + tx * 4 + j;
      float v = dxi + pn[col] - 2.0f * acc[i][j];
      tmp[j] = v;
      lmax = fmaxf(lmax, v);
    }
    float4 cv = make_float4(tmp[0], tmp[1], tmp[2], tmp[3]);
    *(float4*)(C + (size_t)row * K_PTS + k0 + tx * 4) = cv;
  }
  lmax = wave_reduce_max(lmax);
  __shared__ float wmax[4];
  int lane = tid & 63, wv = tid >> 6;
  if (lane == 0) wmax[wv] = lmax;
  __syncthreads();
  if (tid == 0) {
    float m = fmaxf(fmaxf(wmax[0], wmax[1]), fmaxf(wmax[2], wmax[3]));
    atomicMax((int*)maxbits, __float_as_int(m));  // valid: global max is positive
  }
}

// ---------------------------------------------------------------- K_eps = exp(C * factor), in place
__global__ __launch_bounds__(256) void expk_kernel(float* __restrict__ C,
                                                   const unsigned int* __restrict__ maxbits) {
  float cmax = __int_as_float((int)*maxbits);
  float factor = -1.0f / ((cmax + 1e-8f) * EPS_F);
  size_t idx = (size_t)blockIdx.x * 256 + threadIdx.x;
  float4* C4 = (float4*)C;
  float4 c = C4[idx];
  c.x = expf(c.x * factor);
  c.y = expf(c.y * factor);
  c.z = expf(c.z * factor);
  c.w = expf(c.w * factor);
  C4[idx] = c;
}

// ---------------------------------------------------------------- fused Sinkhorn pass
// Computes v = NU/(accum_prev + 1e-8) (or ones if FIRST), then per row:
//   u_i = MU/(K_eps[i,:]·v + 1e-8), and accumulates K_eps^T·u into accum_next.
template <bool FIRST>
__global__ __launch_bounds__(256) void pass_kernel(const float* __restrict__ Keps,
                                                   const float* __restrict__ accum_prev,
                                                   float* __restrict__ accum_next,
                                                   float* __restrict__ u) {
  const int lane = threadIdx.x & 63;
  const int wv = threadIdx.x >> 6;
  const int gw = blockIdx.x * 4 + wv;
  const int nw = gridDim.x * 4;
  float4 vf[4];
#pragma unroll
  for (int j = 0; j < 4; j++) {
    if (FIRST) {
      vf[j] = make_float4(1.f, 1.f, 1.f, 1.f);
    } else {
      const float4 a = *(const float4*)(accum_prev + j * 256 + lane * 4);
      vf[j] = make_float4(NU_F / (a.x + 1e-8f), NU_F / (a.y + 1e-8f),
                          NU_F / (a.z + 1e-8f), NU_F / (a.w + 1e-8f));
    }
  }
  float4 acc[4];
#pragma unroll
  for (int j = 0; j < 4; j++) acc[j] = make_float4(0.f, 0.f, 0.f, 0.f);

  for (int r = gw; r < N_PTS; r += nw) {
    const float4* row = (const float4*)(Keps + (size_t)r * K_PTS);
    float4 f[4];
#pragma unroll
    for (int j = 0; j < 4; j++) f[j] = row[j * 64 + lane];
    float s = 0.f;
#pragma unroll
    for (int j = 0; j < 4; j++)
      s += f[j].x * vf[j].x + f[j].y * vf[j].y + f[j].z * vf[j].z + f[j].w * vf[j].w;
    s = wave_reduce_sum(s);
    float ui = MU_F / (s + 1e-8f);
    if (lane == 0) u[r] = ui;
#pragma unroll
    for (int j = 0; j < 4; j++) {
      acc[j].x += ui * f[j].x;
      acc[j].y += ui * f[j].y;
      acc[j].z += ui * f[j].z;
      acc[j].w += ui * f[j].w;
    }
  }
  __shared__ float red[4][1024];
#pragma unroll
  for (int j = 0; j < 4; j++)
    *(float4*)&red[wv][j * 256 + lane * 4] = acc[j];
  __syncthreads();
  const int c = threadIdx.x * 4;
  float4 s0 = *(float4*)&red[0][c];
  float4 s1 = *(float4*)&red[1][c];
  float4 s2 = *(float4*)&red[2][c];
  float4 s3 = *(float4*)&red[3][c];
  atomicAdd(accum_next + c + 0, s0.x + s1.x + s2.x + s3.x);
  atomicAdd(accum_next + c + 1, s0.y + s1.y + s2.y + s3.y);
  atomicAdd(accum_next + c + 2, s0.z + s1.z + s2.z + s3.z);
  atomicAdd(accum_next + c + 3, s0.w + s1.w + s2.w + s3.w);
}

// ---------------------------------------------------------------- final: T = u*K*v, loss = sum(T * C), C = -eps*ln(K)
__global__ __launch_bounds__(256) void final_kernel(const float* __restrict__ Keps,
                                                    const float* __restrict__ u,
                                                    const float* __restrict__ accum_last,
                                                    float* __restrict__ T,
                                                    float* __restrict__ loss) {
  const size_t tid = (size_t)blockIdx.x * 256 + threadIdx.x;
  const size_t total_threads = (size_t)gridDim.x * 256;
  const size_t total_f4 = (size_t)N_PTS * K_PTS / 4;
  const float4* K4 = (const float4*)Keps;
  float4* T4 = (float4*)T;
  float lsum = 0.f;
  for (size_t f = tid; f < total_f4; f += total_threads) {
    size_t e = f * 4;
    int row = (int)(e >> 10);
    int col = (int)(e & 1023);
    float ui = u[row];
    float4 k = K4[f];
    float4 a = *(const float4*)(accum_last + col);
    float4 t;
    t.x = ui * k.x * (NU_F / (a.x + 1e-8f));
    t.y = ui * k.y * (NU_F / (a.y + 1e-8f));
    t.z = ui * k.z * (NU_F / (a.z + 1e-8f));
    t.w = ui * k.w * (NU_F / (a.w + 1e-8f));
    T4[f] = t;
    lsum += t.x * (-EPS_F * logf(k.x));
    lsum += t.y * (-EPS_F * logf(k.y));
    lsum += t.z * (-EPS_F * logf(k.z));
    lsum += t.w * (-EPS_F * logf(k.w));
  }
  lsum = wave_reduce_sum(lsum);
  __shared__ float wsum[4];
  int lane = threadIdx.x & 63, wv = threadIdx.x >> 6;
  if (lane == 0) wsum[wv] = lsum;
  __syncthreads();
  if (threadIdx.x == 0) atomicAdd(loss, wsum[0] + wsum[1] + wsum[2] + wsum[3]);
}

// ---------------------------------------------------------------- launcher
extern "C" void kernel_launch(void* const* d_in, const int* in_sizes, int n_in,
                              void* d_out, int out_size, void* d_ws, size_t ws_size,
                              hipStream_t stream) {
  const float* x = (const float*)d_in[0];
  const float* p = (const float*)d_in[1];
  float* T = (float*)d_out;
  float* loss = (float*)d_out + (size_t)N_PTS * K_PTS;

  float* wsf = (float*)d_ws;
  float* Keps = wsf;                                   // 16M floats (C, then K_eps in place)
  float* u = wsf + (size_t)N_PTS * K_PTS;              // 16384
  float* dx = u + N_PTS;                               // 16384
  float* pn = dx + N_PTS;                              // 1024
  float* accum = pn + K_PTS;                           // 21*1024
  unsigned int* maxbits = (unsigned int*)(accum + (ITERS + 1) * K_PTS);

  init_kernel<<<((ITERS + 1) * K_PTS + 255) / 256, 256, 0, stream>>>(accum, maxbits, loss);
  rownorm_kernel<<<N_PTS / 4, 256, 0, stream>>>(x, dx, N_PTS);
  rownorm_kernel<<<K_PTS / 4, 256, 0, stream>>>(p, pn, K_PTS);
  gemm_kernel<<<dim3(K_PTS / 64, N_PTS / 64), 256, 0, stream>>>(x, p, dx, pn, Keps, maxbits);
  expk_kernel<<<(N_PTS * K_PTS) / (4 * 256), 256, 0, stream>>>(Keps, maxbits);

  pass_kernel<true><<<512, 256, 0, stream>>>(Keps, nullptr, accum + 1 * K_PTS, u);
  for (int t = 2; t <= ITERS; t++)
    pass_kernel<false><<<512, 256, 0, stream>>>(Keps, accum + (size_t)(t - 1) * K_PTS,
                                                accum + (size_t)t * K_PTS, u);

  final_kernel<<<4096, 256, 0, stream>>>(Keps, u, accum + (size_t)ITERS * K_PTS, T, loss);
}

// Round 2
// 621.689 us; speedup vs baseline: 2.5367x; 2.5367x over previous
//
#include <hip/hip_runtime.h>
#include <cstddef>
#include <cstdint>

#define N_PTS 16384
#define K_PTS 1024
#define D_DIM 512
#define EPS_F 0.1f
#define ITERS 20
#define MU_F (1.0f/16384.0f)
#define NU_F (1.0f/1024.0f)

typedef float f32x4 __attribute__((ext_vector_type(4)));
typedef short s16x8 __attribute__((ext_vector_type(8)));

__device__ __forceinline__ float wave_reduce_sum(float s) {
#pragma unroll
  for (int off = 32; off > 0; off >>= 1) s += __shfl_xor(s, off, 64);
  return s;
}
__device__ __forceinline__ float wave_reduce_max(float s) {
#pragma unroll
  for (int off = 32; off > 0; off >>= 1) s = fmaxf(s, __shfl_xor(s, off, 64));
  return s;
}
__device__ __forceinline__ unsigned short f2bf(float f) {  // RNE, finite inputs
  unsigned int b = __float_as_uint(f);
  b += 0x7fffu + ((b >> 16) & 1u);
  return (unsigned short)(b >> 16);
}
__device__ __forceinline__ float bf2f(unsigned short h) {
  return __uint_as_float(((unsigned int)h) << 16);
}
__device__ __forceinline__ void unpack2(unsigned int w, float& f0, float& f1) {
  f0 = __uint_as_float(w << 16);
  f1 = __uint_as_float(w & 0xffff0000u);
}

// ---------------------------------------------------------------- init
__global__ __launch_bounds__(256) void init_kernel(float* __restrict__ accum,
                                                   unsigned int* __restrict__ maxbits,
                                                   float* __restrict__ loss) {
  int i = blockIdx.x * 256 + threadIdx.x;
  const int total = (ITERS + 1) * 8 * K_PTS;
  if (i < total) accum[i] = 0.0f;
  if (blockIdx.x == 0 && threadIdx.x == 0) { *maxbits = 0u; *loss = 0.0f; }
}

// ---------------------------------------------------------------- row norms
__global__ __launch_bounds__(256) void rownorm_kernel(const float* __restrict__ A,
                                                      float* __restrict__ out, int rows) {
  int wave = (blockIdx.x * 256 + threadIdx.x) >> 6;
  int lane = threadIdx.x & 63;
  if (wave >= rows) return;
  const float4* rp = (const float4*)(A + (size_t)wave * D_DIM);
  float4 a = rp[lane];
  float4 b = rp[lane + 64];
  float s = a.x*a.x + a.y*a.y + a.z*a.z + a.w*a.w
          + b.x*b.x + b.y*b.y + b.z*b.z + b.w*b.w;
  s = wave_reduce_sum(s);
  if (lane == 0) out[wave] = s;
}

// ---------------------------------------------------------------- split-bf16 MFMA GEMM
// C = dx + pn - 2*x@p^T  (fp32 out, written to d_out scratch), track global max.
// x ~ xh + xl (bf16 hi/lo); dot = xh*ph + xh*pl + xl*ph (drop ll, rel err ~2^-17).
#define LDSW 40  // 32 bf16 + 8 pad (bank-conflict break)
__global__ __launch_bounds__(256) void gemm_kernel(const float* __restrict__ X,
                                                   const float* __restrict__ P,
                                                   const float* __restrict__ dx,
                                                   const float* __restrict__ pn,
                                                   float* __restrict__ C,
                                                   unsigned int* __restrict__ maxbits) {
  __shared__ __align__(16) unsigned short Ah[128 * LDSW];
  __shared__ __align__(16) unsigned short Al[128 * LDSW];
  __shared__ __align__(16) unsigned short Bh[128 * LDSW];
  __shared__ __align__(16) unsigned short Bl[128 * LDSW];

  const int tid = threadIdx.x;
  const int lane = tid & 63, wv = tid >> 6;
  const int wm = wv >> 1, wn = wv & 1;
  const int m0 = blockIdx.y * 128, k0 = blockIdx.x * 128;
  const int lrow = tid >> 1, lhalf = tid & 1;

  const float* xrow = X + (size_t)(m0 + lrow) * D_DIM + lhalf * 16;
  const float* prow = P + (size_t)(k0 + lrow) * D_DIM + lhalf * 16;
  const int ldsoff = lrow * LDSW + lhalf * 16;

  f32x4 acc[4][4] = {};

  for (int d0 = 0; d0 < D_DIM; d0 += 32) {
    float av[16], bv[16];
    {
      const float4* xp = (const float4*)(xrow + d0);
      const float4* pp = (const float4*)(prow + d0);
#pragma unroll
      for (int q = 0; q < 4; q++) {
        float4 a = xp[q], b = pp[q];
        av[q*4+0]=a.x; av[q*4+1]=a.y; av[q*4+2]=a.z; av[q*4+3]=a.w;
        bv[q*4+0]=b.x; bv[q*4+1]=b.y; bv[q*4+2]=b.z; bv[q*4+3]=b.w;
      }
    }
    unsigned int ahu[8], alu[8], bhu[8], blu[8];
#pragma unroll
    for (int j = 0; j < 8; j++) {
      float f0 = av[2*j], f1 = av[2*j+1];
      unsigned short h0 = f2bf(f0), h1 = f2bf(f1);
      unsigned short l0 = f2bf(f0 - bf2f(h0)), l1 = f2bf(f1 - bf2f(h1));
      ahu[j] = (unsigned int)h0 | ((unsigned int)h1 << 16);
      alu[j] = (unsigned int)l0 | ((unsigned int)l1 << 16);
      f0 = bv[2*j]; f1 = bv[2*j+1];
      h0 = f2bf(f0); h1 = f2bf(f1);
      l0 = f2bf(f0 - bf2f(h0)); l1 = f2bf(f1 - bf2f(h1));
      bhu[j] = (unsigned int)h0 | ((unsigned int)h1 << 16);
      blu[j] = (unsigned int)l0 | ((unsigned int)l1 << 16);
    }
    __syncthreads();  // protect previous iteration's fragment reads
    *(uint4*)&Ah[ldsoff]     = make_uint4(ahu[0], ahu[1], ahu[2], ahu[3]);
    *(uint4*)&Ah[ldsoff + 8] = make_uint4(ahu[4], ahu[5], ahu[6], ahu[7]);
    *(uint4*)&Al[ldsoff]     = make_uint4(alu[0], alu[1], alu[2], alu[3]);
    *(uint4*)&Al[ldsoff + 8] = make_uint4(alu[4], alu[5], alu[6], alu[7]);
    *(uint4*)&Bh[ldsoff]     = make_uint4(bhu[0], bhu[1], bhu[2], bhu[3]);
    *(uint4*)&Bh[ldsoff + 8] = make_uint4(bhu[4], bhu[5], bhu[6], bhu[7]);
    *(uint4*)&Bl[ldsoff]     = make_uint4(blu[0], blu[1], blu[2], blu[3]);
    *(uint4*)&Bl[ldsoff + 8] = make_uint4(blu[4], blu[5], blu[6], blu[7]);
    __syncthreads();

    const int offA = (wm * 64 + (lane & 15)) * LDSW + (lane >> 4) * 8;
    const int offB = (wn * 64 + (lane & 15)) * LDSW + (lane >> 4) * 8;
    s16x8 ah[4], al[4], bh[4], bl[4];
#pragma unroll
    for (int i = 0; i < 4; i++) {
      ah[i] = *(const s16x8*)&Ah[offA + i * 16 * LDSW];
      al[i] = *(const s16x8*)&Al[offA + i * 16 * LDSW];
      bh[i] = *(const s16x8*)&Bh[offB + i * 16 * LDSW];
      bl[i] = *(const s16x8*)&Bl[offB + i * 16 * LDSW];
    }
#pragma unroll
    for (int mi = 0; mi < 4; mi++)
#pragma unroll
      for (int ni = 0; ni < 4; ni++) {
        acc[mi][ni] = __builtin_amdgcn_mfma_f32_16x16x32_bf16(ah[mi], bh[ni], acc[mi][ni], 0, 0, 0);
        acc[mi][ni] = __builtin_amdgcn_mfma_f32_16x16x32_bf16(ah[mi], bl[ni], acc[mi][ni], 0, 0, 0);
        acc[mi][ni] = __builtin_amdgcn_mfma_f32_16x16x32_bf16(al[mi], bh[ni], acc[mi][ni], 0, 0, 0);
      }
  }

  // epilogue: C/D layout col=lane&15, row=(lane>>4)*4+reg  [m89-verified]
  float lmax = -3.4e38f;
#pragma unroll
  for (int mi = 0; mi < 4; mi++) {
    int rb = m0 + wm * 64 + mi * 16 + (lane >> 4) * 4;
    float dxv[4];
#pragma unroll
    for (int r = 0; r < 4; r++) dxv[r] = dx[rb + r];
#pragma unroll
    for (int ni = 0; ni < 4; ni++) {
      int c = k0 + wn * 64 + ni * 16 + (lane & 15);
      float pnc = pn[c];
#pragma unroll
      for (int r = 0; r < 4; r++) {
        float val = dxv[r] + pnc - 2.0f * acc[mi][ni][r];
        C[(size_t)(rb + r) * K_PTS + c] = val;
        lmax = fmaxf(lmax, val);
      }
    }
  }
  lmax = wave_reduce_max(lmax);
  __shared__ float wmax[4];
  if (lane == 0) wmax[wv] = lmax;
  __syncthreads();
  if (tid == 0) {
    float m = fmaxf(fmaxf(wmax[0], wmax[1]), fmaxf(wmax[2], wmax[3]));
    atomicMax((int*)maxbits, __float_as_int(m));  // global max is positive
  }
}

// ---------------------------------------------------------------- K_eps = bf16(exp(C * factor))
__global__ __launch_bounds__(256) void expk_kernel(const float* __restrict__ C,
                                                   unsigned short* __restrict__ Kb,
                                                   const unsigned int* __restrict__ maxbits) {
  float cmax = __int_as_float((int)*maxbits);
  float factor = -1.0f / ((cmax + 1e-8f) * EPS_F);
  size_t g = (size_t)blockIdx.x * 256 + threadIdx.x;  // 8 elems per thread
  const float4* C4 = (const float4*)(C + g * 8);
  float4 c0 = C4[0], c1 = C4[1];
  float k[8];
  k[0]=__expf(c0.x*factor); k[1]=__expf(c0.y*factor); k[2]=__expf(c0.z*factor); k[3]=__expf(c0.w*factor);
  k[4]=__expf(c1.x*factor); k[5]=__expf(c1.y*factor); k[6]=__expf(c1.z*factor); k[7]=__expf(c1.w*factor);
  unsigned int u0 = (unsigned int)f2bf(k[0]) | ((unsigned int)f2bf(k[1]) << 16);
  unsigned int u1 = (unsigned int)f2bf(k[2]) | ((unsigned int)f2bf(k[3]) << 16);
  unsigned int u2 = (unsigned int)f2bf(k[4]) | ((unsigned int)f2bf(k[5]) << 16);
  unsigned int u3 = (unsigned int)f2bf(k[6]) | ((unsigned int)f2bf(k[7]) << 16);
  ((uint4*)Kb)[g] = make_uint4(u0, u1, u2, u3);
}

// ---------------------------------------------------------------- fused Sinkhorn pass (bf16 K)
// v = NU/(sum_8copies(accum_prev)+1e-8) (ones if FIRST); per row: u_i = MU/(K[i,:]·v+1e-8);
// accumulate K^T·u into accum_next[blockIdx&7] (8-way split atomics).
template <bool FIRST>
__global__ __launch_bounds__(256) void pass_kernel(const unsigned short* __restrict__ Kb,
                                                   const float* __restrict__ accum_prev,
                                                   float* __restrict__ accum_next,
                                                   float* __restrict__ u) {
  __shared__ float v_lds[K_PTS];
  __shared__ float red[4][K_PTS];
  const int tid = threadIdx.x;
  // stage v (4 cols per thread)
  if (FIRST) {
    *(float4*)&v_lds[tid * 4] = make_float4(1.f, 1.f, 1.f, 1.f);
  } else {
    float4 s = make_float4(0.f, 0.f, 0.f, 0.f);
#pragma unroll
    for (int c = 0; c < 8; c++) {
      float4 a = *(const float4*)&accum_prev[c * K_PTS + tid * 4];
      s.x += a.x; s.y += a.y; s.z += a.z; s.w += a.w;
    }
    *(float4*)&v_lds[tid * 4] = make_float4(NU_F/(s.x+1e-8f), NU_F/(s.y+1e-8f),
                                            NU_F/(s.z+1e-8f), NU_F/(s.w+1e-8f));
  }
  __syncthreads();

  const int lane = tid & 63, wv = tid >> 6;
  float vr[16];
#pragma unroll
  for (int q = 0; q < 4; q++) {
    float4 t = *(const float4*)&v_lds[lane * 16 + q * 4];
    vr[q*4+0]=t.x; vr[q*4+1]=t.y; vr[q*4+2]=t.z; vr[q*4+3]=t.w;
  }
  float ca[16] = {};
  const int gw = blockIdx.x * 4 + wv;
  for (int r = gw; r < N_PTS; r += 4096) {
    const uint4* rp = (const uint4*)(Kb + (size_t)r * K_PTS);
    uint4 w0 = rp[lane * 2], w1 = rp[lane * 2 + 1];
    float f[16];
    unpack2(w0.x, f[0], f[1]);   unpack2(w0.y, f[2], f[3]);
    unpack2(w0.z, f[4], f[5]);   unpack2(w0.w, f[6], f[7]);
    unpack2(w1.x, f[8], f[9]);   unpack2(w1.y, f[10], f[11]);
    unpack2(w1.z, f[12], f[13]); unpack2(w1.w, f[14], f[15]);
    float s = 0.f;
#pragma unroll
    for (int j = 0; j < 16; j++) s += f[j] * vr[j];
    s = wave_reduce_sum(s);
    float ui = MU_F / (s + 1e-8f);
    if (lane == 0) u[r] = ui;
#pragma unroll
    for (int j = 0; j < 16; j++) ca[j] += ui * f[j];
  }
#pragma unroll
  for (int q = 0; q < 4; q++)
    *(float4*)&red[wv][lane * 16 + q * 4] = make_float4(ca[q*4+0], ca[q*4+1], ca[q*4+2], ca[q*4+3]);
  __syncthreads();
  float4 s0 = *(float4*)&red[0][tid * 4];
  float4 s1 = *(float4*)&red[1][tid * 4];
  float4 s2 = *(float4*)&red[2][tid * 4];
  float4 s3 = *(float4*)&red[3][tid * 4];
  float* dst = accum_next + (blockIdx.x & 7) * K_PTS + tid * 4;
  atomicAdd(dst + 0, s0.x + s1.x + s2.x + s3.x);
  atomicAdd(dst + 1, s0.y + s1.y + s2.y + s3.y);
  atomicAdd(dst + 2, s0.z + s1.z + s2.z + s3.z);
  atomicAdd(dst + 3, s0.w + s1.w + s2.w + s3.w);
}

// ---------------------------------------------------------------- final: T = u*k*v, loss = sum(T * (-eps*ln k))
__global__ __launch_bounds__(256) void final_kernel(const unsigned short* __restrict__ Kb,
                                                    const float* __restrict__ u,
                                                    const float* __restrict__ accum_last,
                                                    float* __restrict__ T,
                                                    float* __restrict__ loss) {
  __shared__ float v_lds[K_PTS];
  const int tid = threadIdx.x;
  {
    float4 s = make_float4(0.f, 0.f, 0.f, 0.f);
#pragma unroll
    for (int c = 0; c < 8; c++) {
      float4 a = *(const float4*)&accum_last[c * K_PTS + tid * 4];
      s.x += a.x; s.y += a.y; s.z += a.z; s.w += a.w;
    }
    *(float4*)&v_lds[tid * 4] = make_float4(NU_F/(s.x+1e-8f), NU_F/(s.y+1e-8f),
                                            NU_F/(s.z+1e-8f), NU_F/(s.w+1e-8f));
  }
  __syncthreads();

  float lsum = 0.f;
  const unsigned int ngroups = (unsigned int)(N_PTS) * K_PTS / 8;
  for (unsigned int g = blockIdx.x * 256 + tid; g < ngroups; g += 2048u * 256u) {
    unsigned int e = g * 8;
    int row = (int)(e >> 10);
    int col = (int)(e & 1023);
    uint4 w = ((const uint4*)Kb)[g];
    float ui = u[row];
    float f[8];
    unpack2(w.x, f[0], f[1]); unpack2(w.y, f[2], f[3]);
    unpack2(w.z, f[4], f[5]); unpack2(w.w, f[6], f[7]);
    float4 v0 = *(const float4*)&v_lds[col];
    float4 v1 = *(const float4*)&v_lds[col + 4];
    float t[8];
    t[0]=ui*f[0]*v0.x; t[1]=ui*f[1]*v0.y; t[2]=ui*f[2]*v0.z; t[3]=ui*f[3]*v0.w;
    t[4]=ui*f[4]*v1.x; t[5]=ui*f[5]*v1.y; t[6]=ui*f[6]*v1.z; t[7]=ui*f[7]*v1.w;
    float4* Tp = (float4*)(T + e);
    Tp[0] = make_float4(t[0], t[1], t[2], t[3]);
    Tp[1] = make_float4(t[4], t[5], t[6], t[7]);
#pragma unroll
    for (int j = 0; j < 8; j++) lsum += t[j] * (-EPS_F * __logf(f[j]));
  }
  lsum = wave_reduce_sum(lsum);
  __shared__ float wsum[4];
  int lane = tid & 63, wv = tid >> 6;
  if (lane == 0) wsum[wv] = lsum;
  __syncthreads();
  if (tid == 0) atomicAdd(loss, wsum[0] + wsum[1] + wsum[2] + wsum[3]);
}

// ---------------------------------------------------------------- launcher
extern "C" void kernel_launch(void* const* d_in, const int* in_sizes, int n_in,
                              void* d_out, int out_size, void* d_ws, size_t ws_size,
                              hipStream_t stream) {
  const float* x = (const float*)d_in[0];
  const float* p = (const float*)d_in[1];
  float* T = (float*)d_out;
  float* loss = (float*)d_out + (size_t)N_PTS * K_PTS;
  float* Cscratch = (float*)d_out;  // C staged in d_out between gemm and expk

  unsigned short* Kb = (unsigned short*)d_ws;                 // 32 MB bf16 K_eps
  float* u = (float*)(Kb + (size_t)N_PTS * K_PTS);            // 16384
  float* dx = u + N_PTS;                                      // 16384
  float* pn = dx + N_PTS;                                     // 1024
  float* accum = pn + K_PTS;                                  // 21 * 8 * 1024
  unsigned int* maxbits = (unsigned int*)(accum + (ITERS + 1) * 8 * K_PTS);

  init_kernel<<<((ITERS + 1) * 8 * K_PTS + 255) / 256, 256, 0, stream>>>(accum, maxbits, loss);
  rownorm_kernel<<<N_PTS / 4, 256, 0, stream>>>(x, dx, N_PTS);
  rownorm_kernel<<<K_PTS / 4, 256, 0, stream>>>(p, pn, K_PTS);
  gemm_kernel<<<dim3(K_PTS / 128, N_PTS / 128), 256, 0, stream>>>(x, p, dx, pn, Cscratch, maxbits);
  expk_kernel<<<(N_PTS * K_PTS) / (8 * 256), 256, 0, stream>>>(Cscratch, Kb, maxbits);

  pass_kernel<true><<<1024, 256, 0, stream>>>(Kb, nullptr, accum + 1 * 8 * K_PTS, u);
  for (int t = 2; t <= ITERS; t++)
    pass_kernel<false><<<1024, 256, 0, stream>>>(Kb, accum + (size_t)(t - 1) * 8 * K_PTS,
                                                 accum + (size_t)t * 8 * K_PTS, u);

  final_kernel<<<2048, 256, 0, stream>>>(Kb, u, accum + (size_t)ITERS * 8 * K_PTS, T, loss);
}